// Round 3
// baseline (875.855 us; speedup 1.0000x reference)
//
#include <hip/hip_runtime.h>

// 3-layer sparse conv, gather formulation (zero atomics in conv1/conv2).
// R3: occupancy fix — split independent dims across blockIdx.y to raise wave
// count (conv1: j-split x2, conv2: j-split x4, conv3: k-split x3 + atomics),
// and make all stores full-64B-sector to kill write amplification.

#define TPB 256

__global__ void __launch_bounds__(TPB)
k_build(const int* __restrict__ mi, const int* __restrict__ mo,
        int* __restrict__ tbl, int L, int n_out) {
  int k = blockIdx.y;
  int p = blockIdx.x * TPB + threadIdx.x;
  if (p >= L) return;
  int out = mo[(size_t)k * L + p];
  bool valid = out < n_out;                 // pads point at dummy row n_out
  if (__ballot(valid) == 0ull) return;      // pads are a contiguous tail
  if (valid) tbl[(size_t)k * n_out + out] = mi[(size_t)k * L + p];
}

// conv1: 8 -> 64, 27 offsets. lane = output row, blockIdx.y = j-half (32 ch).
// Stores h1 = relu(acc + b1) as one 128B contiguous chunk per lane.
__global__ void __launch_bounds__(TPB)
k_conv1(const float* __restrict__ x, const float* __restrict__ W1,
        const float* __restrict__ b1, const int* __restrict__ t1,
        float* __restrict__ h1, int n1) {
  int r = blockIdx.x * TPB + threadIdx.x;
  if (r >= n1) return;
  int j0 = blockIdx.y * 32;
  float acc[32];
#pragma unroll
  for (int j = 0; j < 32; ++j) acc[j] = 0.f;
#pragma unroll 1
  for (int k = 0; k < 27; ++k) {
    int idx = t1[(size_t)k * n1 + r];
    bool v = idx >= 0;
    if (__ballot(v) == 0ull) continue;
    const float4* xr = (const float4*)(x + (size_t)(v ? idx : 0) * 8);
    float4 a = xr[0], b = xr[1];
    if (!v) { a = make_float4(0.f,0.f,0.f,0.f); b = make_float4(0.f,0.f,0.f,0.f); }
    float xv[8] = {a.x, a.y, a.z, a.w, b.x, b.y, b.z, b.w};
    const float* __restrict__ Wk = W1 + (size_t)k * 512 + j0;   // (8,64) col-slice
#pragma unroll
    for (int i = 0; i < 8; ++i)
#pragma unroll
      for (int j = 0; j < 32; ++j)
        acc[j] = fmaf(xv[i], Wk[i * 64 + j], acc[j]);
  }
  float4* yr = (float4*)(h1 + (size_t)r * 64 + j0);
#pragma unroll
  for (int q = 0; q < 8; ++q) {
    float4 o;
    o.x = fmaxf(acc[4*q+0] + b1[j0+4*q+0], 0.f);
    o.y = fmaxf(acc[4*q+1] + b1[j0+4*q+1], 0.f);
    o.z = fmaxf(acc[4*q+2] + b1[j0+4*q+2], 0.f);
    o.w = fmaxf(acc[4*q+3] + b1[j0+4*q+3], 0.f);
    yr[q] = o;
  }
}

// conv2: 64 -> 64, 8 offsets. lane = output row, blockIdx.y = j-quarter (16 ch).
// Gathers full h1 row (zero row n1 for invalid); stores 64B chunk.
__global__ void __launch_bounds__(TPB)
k_conv2(const float* __restrict__ h1, const float* __restrict__ W2,
        const float* __restrict__ b2, const int* __restrict__ t2,
        float* __restrict__ h2, int n1, int n2) {
  int r = blockIdx.x * TPB + threadIdx.x;
  if (r >= n2) return;
  int j0 = blockIdx.y * 16;
  float acc[16];
#pragma unroll
  for (int j = 0; j < 16; ++j) acc[j] = 0.f;
#pragma unroll 1
  for (int k = 0; k < 8; ++k) {
    int idx = t2[(size_t)k * n2 + r];
    int row = idx >= 0 ? idx : n1;          // zero row
    const float4* xr = (const float4*)(h1 + (size_t)row * 64);
    const float* __restrict__ Wk = W2 + (size_t)k * 4096 + j0;  // (64,64) col-slice
#pragma unroll 4
    for (int c = 0; c < 16; ++c) {
      float4 xv = xr[c];
#pragma unroll
      for (int j = 0; j < 16; ++j) {
        acc[j] = fmaf(xv.x, Wk[(4*c+0)*64 + j], acc[j]);
        acc[j] = fmaf(xv.y, Wk[(4*c+1)*64 + j], acc[j]);
        acc[j] = fmaf(xv.z, Wk[(4*c+2)*64 + j], acc[j]);
        acc[j] = fmaf(xv.w, Wk[(4*c+3)*64 + j], acc[j]);
      }
    }
  }
  float4* yr = (float4*)(h2 + (size_t)r * 64 + j0);
#pragma unroll
  for (int q = 0; q < 4; ++q) {
    float4 o;
    o.x = fmaxf(acc[4*q+0] + b2[j0+4*q+0], 0.f);
    o.y = fmaxf(acc[4*q+1] + b2[j0+4*q+1], 0.f);
    o.z = fmaxf(acc[4*q+2] + b2[j0+4*q+2], 0.f);
    o.w = fmaxf(acc[4*q+3] + b2[j0+4*q+3], 0.f);
    yr[q] = o;
  }
}

// conv3: 64 -> 8, 27 offsets split 3 ways over blockIdx.y (k in [9y, 9y+9)).
// Partial sums atomically added to pre-zeroed d_out; b3 folded into y==1.
__global__ void __launch_bounds__(TPB)
k_conv3(const float* __restrict__ h2, const float* __restrict__ W3,
        const float* __restrict__ b3, const int* __restrict__ t3,
        float* __restrict__ out, int n2) {
  int r = blockIdx.x * TPB + threadIdx.x;
  if (r >= n2) return;
  int kbase = blockIdx.y * 9;
  float acc[8];
  if (blockIdx.y == 1) {
#pragma unroll
    for (int j = 0; j < 8; ++j) acc[j] = b3[j];
  } else {
#pragma unroll
    for (int j = 0; j < 8; ++j) acc[j] = 0.f;
  }
#pragma unroll 1
  for (int kk = 0; kk < 9; ++kk) {
    int k = kbase + kk;
    int idx = t3[(size_t)k * n2 + r];
    int row = idx >= 0 ? idx : n2;          // zero row
    const float4* xr = (const float4*)(h2 + (size_t)row * 64);
    const float* __restrict__ Wk = W3 + (size_t)k * 512;   // (64,8)
#pragma unroll
    for (int c = 0; c < 16; ++c) {
      float4 xv = xr[c];
      float hv[4] = {xv.x, xv.y, xv.z, xv.w};
#pragma unroll
      for (int u = 0; u < 4; ++u)
#pragma unroll
        for (int j = 0; j < 8; ++j)
          acc[j] = fmaf(hv[u], Wk[(4*c+u)*8 + j], acc[j]);
    }
  }
  float* yr = out + (size_t)r * 8;
#pragma unroll
  for (int j = 0; j < 8; ++j) unsafeAtomicAdd(&yr[j], acc[j]);
}

extern "C" void kernel_launch(void* const* d_in, const int* in_sizes, int n_in,
                              void* d_out, int out_size, void* d_ws, size_t ws_size,
                              hipStream_t stream) {
  const float* feats = (const float*)d_in[0];
  const float* W1 = (const float*)d_in[1];
  const float* b1 = (const float*)d_in[2];
  const float* W2 = (const float*)d_in[3];
  const float* b2 = (const float*)d_in[4];
  const float* W3 = (const float*)d_in[5];
  const float* b3 = (const float*)d_in[6];
  const int* m1i = (const int*)d_in[7];
  const int* m1o = (const int*)d_in[8];
  const int* m2i = (const int*)d_in[9];
  const int* m2o = (const int*)d_in[10];
  const int* m3i = (const int*)d_in[11];
  const int* m3o = (const int*)d_in[12];

  int n1 = in_sizes[0] / 8;
  int L1 = in_sizes[7] / 27;
  int L2 = in_sizes[9] / 8;
  int L3 = in_sizes[11] / 27;
  int n2 = out_size / 8;

  // Workspace layout (t1 aliases the y2 region: t1 dead before conv2 writes y2)
  char* ws = (char*)d_ws;
  size_t y1_bytes = (size_t)(n1 + 1) * 64 * sizeof(float);
  size_t y2_bytes = (size_t)(n2 + 1) * 64 * sizeof(float);
  size_t t1_bytes = (size_t)27 * n1 * sizeof(int);
  size_t reg1_bytes = y2_bytes > t1_bytes ? y2_bytes : t1_bytes;
  float* y1 = (float*)ws;                              // h1: (n1+1) x 64
  float* y2 = (float*)(ws + y1_bytes);                 // h2: (n2+1) x 64
  int* t1 = (int*)(ws + y1_bytes);                     // alias (27 x n1)
  int* t2 = (int*)(ws + y1_bytes + reg1_bytes);        // 8 x n2
  int* t3 = (int*)(ws + y1_bytes + reg1_bytes + (size_t)8 * n2 * sizeof(int));

  hipMemsetAsync(t1, 0xFF, t1_bytes, stream);
  hipMemsetAsync(t2, 0xFF, (size_t)8 * n2 * sizeof(int), stream);
  hipMemsetAsync(t3, 0xFF, (size_t)27 * n2 * sizeof(int), stream);
  hipMemsetAsync(d_out, 0, (size_t)out_size * sizeof(float), stream);  // conv3 atomics

  k_build<<<dim3((L1 + TPB - 1) / TPB, 27), TPB, 0, stream>>>(m1i, m1o, t1, L1, n1);
  k_build<<<dim3((L2 + TPB - 1) / TPB, 8), TPB, 0, stream>>>(m2i, m2o, t2, L2, n2);
  k_build<<<dim3((L3 + TPB - 1) / TPB, 27), TPB, 0, stream>>>(m3i, m3o, t3, L3, n2);

  k_conv1<<<dim3((n1 + TPB - 1) / TPB, 2), TPB, 0, stream>>>(feats, W1, b1, t1, y1, n1);

  // zero rows for invalid gathers (y2's zero row lives inside the t1 alias
  // region, so write it only after conv1 has consumed t1)
  hipMemsetAsync(y1 + (size_t)n1 * 64, 0, 64 * sizeof(float), stream);
  hipMemsetAsync(y2 + (size_t)n2 * 64, 0, 64 * sizeof(float), stream);

  k_conv2<<<dim3((n2 + TPB - 1) / TPB, 4), TPB, 0, stream>>>(y1, W2, b2, t2, y2, n1, n2);
  k_conv3<<<dim3((n2 + TPB - 1) / TPB, 3), TPB, 0, stream>>>(y2, W3, b3, t3, (float*)d_out, n2);
}